// Round 21
// baseline (134.274 us; speedup 1.0000x reference)
//
#include <hip/hip_runtime.h>
#include <hip/hip_bf16.h>
#include <math.h>

constexpr int NV = 32000;
constexpr int NE = 256;
constexpr int NH = 512;
constexpr int NB = 128;
constexpr int NS = 512;
constexpr int NX = NH + NE;   // 768, LSTM0 input dim
constexpr int NSC = 8;        // s-chunks for attention partials

typedef __attribute__((ext_vector_type(8))) short short8;   // bf16x8 frag
typedef __attribute__((ext_vector_type(4))) short short4v;  // bf16x4
typedef __attribute__((ext_vector_type(4))) float f32x4;

// -------- workspace layout (float offsets) --------
constexpr size_t OFF_PCTX  = 0;                               // 524288
constexpr size_t OFF_PML   = OFF_PCTX  + (size_t)NB*NSC*NH;   // 2048
constexpr size_t OFF_XBF   = OFF_PML   + (size_t)NB*NSC*2;    // bf16 [128][768]
constexpr size_t OFF_H0NBF = OFF_XBF   + 49152;               // bf16 [128][512]
constexpr size_t OFF_H1NBF = OFF_H0NBF + 32768;
constexpr size_t OFF_H0BFI = OFF_H1NBF + 32768;               // bf16 copy of hidden[0]
constexpr size_t OFF_H1BFI = OFF_H0BFI + 32768;               // bf16 copy of hidden[1]

// d_out layout: pred[128*32000] | new_hidden[2*128*512] | new_cell[2*128*512]
constexpr size_t OUT_HID  = (size_t)NB * NV;
constexpr size_t OUT_CELL = OUT_HID + 2ull * NB * NH;

__device__ inline float sigf(float x) { return 1.0f / (1.0f + expf(-x)); }
__device__ inline short bf16s(float x) {
  __hip_bfloat16 h = __float2bfloat16(x);
  return *reinterpret_cast<short*>(&h);
}

// -------- one-pass online-softmax attention partial, dual chain (r7) -----
__global__ __launch_bounds__(256) void attn_partial_k(
    const float* __restrict__ enc, const float* __restrict__ attn_w,
    float* __restrict__ pctx, float* __restrict__ pml) {
  const int sc = blockIdx.x, b = blockIdx.y;
  const int wv = threadIdx.x >> 6, lane = threadIdx.x & 63;
  const f32x4 wa = *reinterpret_cast<const f32x4*>(attn_w + lane * 4);
  const f32x4 wb = *reinterpret_cast<const f32x4*>(attn_w + 256 + lane * 4);
  float m0 = -INFINITY, l0 = 0.f, m1 = -INFINITY, l1 = 0.f;
  f32x4 a00 = {}, a01 = {}, a10 = {}, a11 = {};
  const float* base = enc + ((size_t)(sc * 64 + wv) * NB + b) * NH;
  for (int i = 0; i < 8; ++i) {
    const float* r0 = base + (size_t)(i * 4) * NB * NH;
    const float* r1 = base + (size_t)((i + 8) * 4) * NB * NH;
    f32x4 e00 = *reinterpret_cast<const f32x4*>(r0 + lane * 4);
    f32x4 e01 = *reinterpret_cast<const f32x4*>(r0 + 256 + lane * 4);
    f32x4 e10 = *reinterpret_cast<const f32x4*>(r1 + lane * 4);
    f32x4 e11 = *reinterpret_cast<const f32x4*>(r1 + 256 + lane * 4);
    float d0 = e00.x * wa.x + e00.y * wa.y + e00.z * wa.z + e00.w * wa.w
             + e01.x * wb.x + e01.y * wb.y + e01.z * wb.z + e01.w * wb.w;
    float d1 = e10.x * wa.x + e10.y * wa.y + e10.z * wa.z + e10.w * wa.w
             + e11.x * wb.x + e11.y * wb.y + e11.z * wb.z + e11.w * wb.w;
#pragma unroll
    for (int off = 32; off; off >>= 1) {
      d0 += __shfl_xor(d0, off);
      d1 += __shfl_xor(d1, off);
    }
    float mn0 = fmaxf(m0, d0), mn1 = fmaxf(m1, d1);
    float s0 = expf(m0 - mn0), s1 = expf(m1 - mn1);
    float p0 = expf(d0 - mn0), p1 = expf(d1 - mn1);
    l0 = l0 * s0 + p0;         l1 = l1 * s1 + p1;
    a00 = a00 * s0 + p0 * e00; a01 = a01 * s0 + p0 * e01;
    a10 = a10 * s1 + p1 * e10; a11 = a11 * s1 + p1 * e11;
    m0 = mn0; m1 = mn1;
  }
  const float Mw = fmaxf(m0, m1);
  const float c0 = expf(m0 - Mw), c1 = expf(m1 - Mw);
  const float lw = l0 * c0 + l1 * c1;
  const f32x4 accA = a00 * c0 + a10 * c1;
  const f32x4 accB = a01 * c0 + a11 * c1;
  __shared__ float sm[4], sl[4], sacc[4][NH];
  if (lane == 0) { sm[wv] = Mw; sl[wv] = lw; }
  *reinterpret_cast<f32x4*>(&sacc[wv][lane * 4]) = accA;
  *reinterpret_cast<f32x4*>(&sacc[wv][256 + lane * 4]) = accB;
  __syncthreads();
  const float M = fmaxf(fmaxf(sm[0], sm[1]), fmaxf(sm[2], sm[3]));
  const float e0 = expf(sm[0] - M), e1 = expf(sm[1] - M),
              e2 = expf(sm[2] - M), e3 = expf(sm[3] - M);
  const int t = threadIdx.x;
  float* outc = pctx + ((size_t)b * NSC + sc) * NH;
#pragma unroll
  for (int q = 0; q < 2; ++q) {
    int h = q * 256 + t;
    outc[h] = sacc[0][h] * e0 + sacc[1][h] * e1 + sacc[2][h] * e2 + sacc[3][h] * e3;
  }
  if (t == 0) {
    pml[((size_t)b * NSC + sc) * 2 + 0] = M;
    pml[((size_t)b * NSC + sc) * 2 + 1] = sl[0] * e0 + sl[1] * e1 + sl[2] * e2 + sl[3] * e3;
  }
}

// -------- merge partials, emit bf16 x (+embedding) + bf16 hidden copies --
__global__ __launch_bounds__(256) void attn_finish_k(
    const float* __restrict__ pctx, const float* __restrict__ pml,
    const float* __restrict__ emb, const int* __restrict__ dec,
    const float* __restrict__ hidden,
    __hip_bfloat16* __restrict__ xbf,
    __hip_bfloat16* __restrict__ h0bf, __hip_bfloat16* __restrict__ h1bf) {
  const int b = blockIdx.x, t = threadIdx.x;
  float ms[NSC];
  float M = -INFINITY;
#pragma unroll
  for (int sc = 0; sc < NSC; ++sc) {
    ms[sc] = pml[((size_t)b * NSC + sc) * 2 + 0];
    M = fmaxf(M, ms[sc]);
  }
  float L = 0.f, es[NSC];
#pragma unroll
  for (int sc = 0; sc < NSC; ++sc) {
    es[sc] = expf(ms[sc] - M);
    L += pml[((size_t)b * NSC + sc) * 2 + 1] * es[sc];
  }
  const float invL = 1.f / L;
#pragma unroll
  for (int q = 0; q < 2; ++q) {
    int h = q * 256 + t;
    float v = 0.f;
#pragma unroll
    for (int sc = 0; sc < NSC; ++sc)
      v += pctx[((size_t)b * NSC + sc) * NH + h] * es[sc];
    xbf[(size_t)b * NX + h] = __float2bfloat16(v * invL);
    h0bf[(size_t)b * NH + h] = __float2bfloat16(hidden[(size_t)b * NH + h]);
    h1bf[(size_t)b * NH + h] =
        __float2bfloat16(hidden[(size_t)(NB * NH) + (size_t)b * NH + h]);
  }
  xbf[(size_t)b * NX + NH + t] = __float2bfloat16(emb[(size_t)dec[b] * NE + t]);
}

// -------- fused LSTM layer: pipelined gates GEMM + in-block pointwise ----
constexpr int LSLAB = 520;
__global__ __launch_bounds__(256, 1) void lstm_fused_k(
    const float* __restrict__ Wx, int Kx, const float* __restrict__ Wh,
    const __hip_bfloat16* __restrict__ Ax, const __hip_bfloat16* __restrict__ Ah,
    const float* __restrict__ b_ih, const float* __restrict__ b_hh,
    const float* __restrict__ c_in,
    float* __restrict__ h_out, float* __restrict__ c_out,
    __hip_bfloat16* __restrict__ hbf_out) {
  __shared__ short wlds[2][8 * LSLAB];
  __shared__ float sg[NB][17];
  const int tid = threadIdx.x, wv = tid >> 6, lane = tid & 63;
  const int l15 = lane & 15, lhi = lane >> 4;
  const int p = blockIdx.x;                  // h-range [p*4, p*4+4)
  const int NCHX = Kx >> 8, NCH = NCHX + 2;
  const int srow = tid >> 6;                 // 0..3
  const int scol = lane * 4;                 // 0..252
  const int soff0 = (scol >> 5) * LSLAB + (scol & 31);

  f32x4 wr[4];
#define LSTAGE_LOAD(c)                                                        \
  {                                                                           \
    const bool fx = (c) < NCHX;                                               \
    const float* Ws = fx ? Wx : Wh;                                           \
    const int Ks = fx ? Kx : NH;                                              \
    const int cb = fx ? (c) * 256 : ((c) - NCHX) * 256;                       \
    _Pragma("unroll")                                                         \
    for (int i = 0; i < 4; ++i)                                               \
      wr[i] = *reinterpret_cast<const f32x4*>(                                \
          Ws + (size_t)(i * NH + p * 4 + srow) * Ks + cb + scol);             \
  }
#define LSTAGE_WRITE(buf)                                                     \
  {                                                                           \
    _Pragma("unroll")                                                         \
    for (int i = 0; i < 4; ++i) {                                             \
      short4v cv;                                                             \
      cv[0] = bf16s(wr[i].x); cv[1] = bf16s(wr[i].y);                         \
      cv[2] = bf16s(wr[i].z); cv[3] = bf16s(wr[i].w);                         \
      *reinterpret_cast<short4v*>((buf) + soff0 + (i * 4 + srow) * 32) = cv;  \
    }                                                                         \
  }

  LSTAGE_LOAD(0);
  LSTAGE_WRITE(wlds[0]);
  __syncthreads();

  f32x4 acc0 = {}, acc1 = {};
  for (int c = 0; c < NCH; ++c) {
    if (c + 1 < NCH) LSTAGE_LOAD(c + 1);
    {
      const bool fx = c < NCHX;
      const __hip_bfloat16* As = fx ? Ax : Ah;
      const int Ks = fx ? Kx : NH;
      const int cb = fx ? c * 256 : (c - NCHX) * 256;
      const short* wb = wlds[c & 1];
      const __hip_bfloat16* ar0 = As + (size_t)(wv * 32 + l15) * Ks + cb + lhi * 8;
      const __hip_bfloat16* ar1 = ar0 + (size_t)16 * Ks;
#pragma unroll
      for (int ks = 0; ks < 8; ++ks) {
        short8 bf = *reinterpret_cast<const short8*>(wb + ks * LSLAB + l15 * 32 + lhi * 8);
        short8 a0 = *reinterpret_cast<const short8*>(ar0 + ks * 32);
        short8 a1 = *reinterpret_cast<const short8*>(ar1 + ks * 32);
        acc0 = __builtin_amdgcn_mfma_f32_16x16x32_bf16(a0, bf, acc0, 0, 0, 0);
        acc1 = __builtin_amdgcn_mfma_f32_16x16x32_bf16(a1, bf, acc1, 0, 0, 0);
      }
    }
    if (c + 1 < NCH) {
      LSTAGE_WRITE(wlds[(c + 1) & 1]);
      __syncthreads();
    }
  }
#pragma unroll
  for (int q = 0; q < 4; ++q) {
    sg[wv * 32 + lhi * 4 + q][l15] = acc0[q];
    sg[wv * 32 + 16 + lhi * 4 + q][l15] = acc1[q];
  }
  __syncthreads();
#pragma unroll
  for (int it = 0; it < 2; ++it) {
    const int item = tid + it * 256;
    const int b = item >> 2, r = item & 3;
    const int h = p * 4 + r;
    float ig = sg[b][0 + r]  + b_ih[0 * NH + h] + b_hh[0 * NH + h];
    float fg = sg[b][4 + r]  + b_ih[1 * NH + h] + b_hh[1 * NH + h];
    float gg = sg[b][8 + r]  + b_ih[2 * NH + h] + b_hh[2 * NH + h];
    float og = sg[b][12 + r] + b_ih[3 * NH + h] + b_hh[3 * NH + h];
    float c = c_in[(size_t)b * NH + h];
    float c2 = sigf(fg) * c + sigf(ig) * tanhf(gg);
    float h2 = sigf(og) * tanhf(c2);
    c_out[(size_t)b * NH + h] = c2;
    h_out[(size_t)b * NH + h] = h2;
    hbf_out[(size_t)b * NH + h] = __float2bfloat16(h2);
  }
#undef LSTAGE_LOAD
#undef LSTAGE_WRITE
}

// -------- FC: pipelined persistent-panel GEMM (r15-proven, 8 panels) -----
constexpr int FC_PANELS = 8;
constexpr int FC_BLOCKS = NV / (16 * FC_PANELS);   // 250
constexpr int SLAB = 520;                          // shorts per ks slab

__global__ __launch_bounds__(256, 1) void gemm_fc_pipe_k(
    const __hip_bfloat16* __restrict__ Abf, const float* __restrict__ W,
    const float* __restrict__ bias, float* __restrict__ out) {
  __shared__ short wlds[2][16 * SLAB];   // ~16.3 KB per buffer
  const int tid = threadIdx.x, wv = tid >> 6, lane = tid & 63;
  const int l15 = lane & 15, lhi = lane >> 4;
  const int nbase = blockIdx.x * (16 * FC_PANELS);

  int soff[8];
#pragma unroll
  for (int i = 0; i < 8; ++i) {
    const int o = i * 1024 + tid * 4;
    const int n = o >> 9, kk = o & 511;
    soff[i] = (kk >> 5) * SLAB + n * 32 + (kk & 31);
  }

  short8 af[2][16];
#pragma unroll
  for (int m = 0; m < 2; ++m) {
    const __hip_bfloat16* ar = Abf + (size_t)(wv * 32 + m * 16 + l15) * NH + lhi * 8;
#pragma unroll
    for (int ks = 0; ks < 16; ++ks)
      af[m][ks] = *reinterpret_cast<const short8*>(ar + ks * 32);
  }

  f32x4 wr[8];
  {
    const float* panel = W + (size_t)nbase * NH;
#pragma unroll
    for (int i = 0; i < 8; ++i)
      wr[i] = *reinterpret_cast<const f32x4*>(panel + i * 1024 + tid * 4);
    short* wb0 = wlds[0];
#pragma unroll
    for (int i = 0; i < 8; ++i) {
      short4v cv;
      cv[0] = bf16s(wr[i].x); cv[1] = bf16s(wr[i].y);
      cv[2] = bf16s(wr[i].z); cv[3] = bf16s(wr[i].w);
      *reinterpret_cast<short4v*>(wb0 + soff[i]) = cv;
    }
  }
  __syncthreads();

  f32x4 s0 = {}, s1 = {};
  int sn0 = -1;
  for (int p = 0; p < FC_PANELS; ++p) {
    if (p < FC_PANELS - 1) {
      const float* panel = W + (size_t)(nbase + (p + 1) * 16) * NH;
#pragma unroll
      for (int i = 0; i < 8; ++i)
        wr[i] = *reinterpret_cast<const f32x4*>(panel + i * 1024 + tid * 4);
    }
    if (sn0 >= 0) {
      const float bv = bias[sn0 + l15];
#pragma unroll
      for (int q = 0; q < 4; ++q) {
        out[(size_t)(wv * 32 + 0 * 16 + lhi * 4 + q) * NV + sn0 + l15] = s0[q] + bv;
        out[(size_t)(wv * 32 + 1 * 16 + lhi * 4 + q) * NV + sn0 + l15] = s1[q] + bv;
      }
    }
    {
      const short* wb = wlds[p & 1];
      f32x4 a0 = {}, a1 = {};
#pragma unroll
      for (int ks = 0; ks < 16; ++ks) {
        short8 bf = *reinterpret_cast<const short8*>(wb + ks * SLAB + l15 * 32 + lhi * 8);
        a0 = __builtin_amdgcn_mfma_f32_16x16x32_bf16(af[0][ks], bf, a0, 0, 0, 0);
        a1 = __builtin_amdgcn_mfma_f32_16x16x32_bf16(af[1][ks], bf, a1, 0, 0, 0);
      }
      s0 = a0; s1 = a1; sn0 = nbase + p * 16;
    }
    if (p < FC_PANELS - 1) {
      short* wbn = wlds[(p + 1) & 1];
#pragma unroll
      for (int i = 0; i < 8; ++i) {
        short4v cv;
        cv[0] = bf16s(wr[i].x); cv[1] = bf16s(wr[i].y);
        cv[2] = bf16s(wr[i].z); cv[3] = bf16s(wr[i].w);
        *reinterpret_cast<short4v*>(wbn + soff[i]) = cv;
      }
      __syncthreads();
    }
  }
  {
    const float bv = bias[sn0 + l15];
#pragma unroll
    for (int q = 0; q < 4; ++q) {
      out[(size_t)(wv * 32 + 0 * 16 + lhi * 4 + q) * NV + sn0 + l15] = s0[q] + bv;
      out[(size_t)(wv * 32 + 1 * 16 + lhi * 4 + q) * NV + sn0 + l15] = s1[q] + bv;
    }
  }
}

extern "C" void kernel_launch(void* const* d_in, const int* in_sizes, int n_in,
                              void* d_out, int out_size, void* d_ws, size_t ws_size,
                              hipStream_t stream) {
  const int*   dec    = (const int*)d_in[0];
  const float* hidden = (const float*)d_in[1];
  const float* cell   = (const float*)d_in[2];
  const float* enc    = (const float*)d_in[3];
  const float* emb    = (const float*)d_in[4];
  const float* attn_w = (const float*)d_in[5];
  // d_in[6] = attn_b (cancels in softmax)
  const float* w_ih0  = (const float*)d_in[7];
  const float* w_hh0  = (const float*)d_in[8];
  const float* b_ih0  = (const float*)d_in[9];
  const float* b_hh0  = (const float*)d_in[10];
  const float* w_ih1  = (const float*)d_in[11];
  const float* w_hh1  = (const float*)d_in[12];
  const float* b_ih1  = (const float*)d_in[13];
  const float* b_hh1  = (const float*)d_in[14];
  const float* fc_w   = (const float*)d_in[15];
  const float* fc_b   = (const float*)d_in[16];
  float* out = (float*)d_out;
  float* ws  = (float*)d_ws;

  float* pctx = ws + OFF_PCTX;
  float* pml  = ws + OFF_PML;
  __hip_bfloat16* xbf   = (__hip_bfloat16*)(ws + OFF_XBF);
  __hip_bfloat16* h0nbf = (__hip_bfloat16*)(ws + OFF_H0NBF);
  __hip_bfloat16* h1nbf = (__hip_bfloat16*)(ws + OFF_H1NBF);
  __hip_bfloat16* h0bf  = (__hip_bfloat16*)(ws + OFF_H0BFI);
  __hip_bfloat16* h1bf  = (__hip_bfloat16*)(ws + OFF_H1BFI);

  attn_partial_k<<<dim3(NSC, NB), 256, 0, stream>>>(enc, attn_w, pctx, pml);
  attn_finish_k<<<NB, 256, 0, stream>>>(pctx, pml, emb, dec, hidden,
                                        xbf, h0bf, h1bf);
  lstm_fused_k<<<NH / 4, 256, 0, stream>>>(w_ih0, NX, w_hh0, xbf, h0bf,
                                           b_ih0, b_hh0, cell,
                                           out + OUT_HID, out + OUT_CELL, h0nbf);
  // TIMING PROBE: layer-1 LSTM launched 6x (idempotent, deterministic).
  // lstm1 = (dur_us - 76.8)/5.
  for (int rep = 0; rep < 6; ++rep) {
    lstm_fused_k<<<NH / 4, 256, 0, stream>>>(w_ih1, NH, w_hh1, h0nbf, h1bf,
                                             b_ih1, b_hh1, cell + NB * NH,
                                             out + OUT_HID + (size_t)NB * NH,
                                             out + OUT_CELL + (size_t)NB * NH,
                                             h1nbf);
  }
  gemm_fc_pipe_k<<<FC_BLOCKS, 256, 0, stream>>>(h1nbf, fc_w, fc_b, out);
}

// Round 22
// 67.632 us; speedup vs baseline: 1.9854x; 1.9854x over previous
//
#include <hip/hip_runtime.h>
#include <hip/hip_bf16.h>
#include <math.h>

constexpr int NV = 32000;
constexpr int NE = 256;
constexpr int NH = 512;
constexpr int NB = 128;
constexpr int NS = 512;
constexpr int NX = NH + NE;   // 768, LSTM0 input dim
constexpr int NSC = 8;        // s-chunks for attention partials

typedef __attribute__((ext_vector_type(8))) short short8;   // bf16x8 frag
typedef __attribute__((ext_vector_type(4))) short short4v;  // bf16x4
typedef __attribute__((ext_vector_type(4))) float f32x4;

// -------- workspace layout (float offsets) --------
constexpr size_t OFF_PCTX  = 0;                               // 524288
constexpr size_t OFF_PML   = OFF_PCTX  + (size_t)NB*NSC*NH;   // 2048
constexpr size_t OFF_XBF   = OFF_PML   + (size_t)NB*NSC*2;    // bf16 [128][768]
constexpr size_t OFF_H0NBF = OFF_XBF   + 49152;               // bf16 [128][512]
constexpr size_t OFF_H1NBF = OFF_H0NBF + 32768;
constexpr size_t OFF_H0BFI = OFF_H1NBF + 32768;               // bf16 copy of hidden[0]
constexpr size_t OFF_H1BFI = OFF_H0BFI + 32768;               // bf16 copy of hidden[1]

// d_out layout: pred[128*32000] | new_hidden[2*128*512] | new_cell[2*128*512]
constexpr size_t OUT_HID  = (size_t)NB * NV;
constexpr size_t OUT_CELL = OUT_HID + 2ull * NB * NH;

__device__ inline float sigf(float x) { return 1.0f / (1.0f + expf(-x)); }
__device__ inline short bf16s(float x) {
  __hip_bfloat16 h = __float2bfloat16(x);
  return *reinterpret_cast<short*>(&h);
}

// -------- one-pass online-softmax attention partial, dual chain (r7) -----
__global__ __launch_bounds__(256) void attn_partial_k(
    const float* __restrict__ enc, const float* __restrict__ attn_w,
    float* __restrict__ pctx, float* __restrict__ pml) {
  const int sc = blockIdx.x, b = blockIdx.y;
  const int wv = threadIdx.x >> 6, lane = threadIdx.x & 63;
  const f32x4 wa = *reinterpret_cast<const f32x4*>(attn_w + lane * 4);
  const f32x4 wb = *reinterpret_cast<const f32x4*>(attn_w + 256 + lane * 4);
  float m0 = -INFINITY, l0 = 0.f, m1 = -INFINITY, l1 = 0.f;
  f32x4 a00 = {}, a01 = {}, a10 = {}, a11 = {};
  const float* base = enc + ((size_t)(sc * 64 + wv) * NB + b) * NH;
  for (int i = 0; i < 8; ++i) {
    const float* r0 = base + (size_t)(i * 4) * NB * NH;
    const float* r1 = base + (size_t)((i + 8) * 4) * NB * NH;
    f32x4 e00 = *reinterpret_cast<const f32x4*>(r0 + lane * 4);
    f32x4 e01 = *reinterpret_cast<const f32x4*>(r0 + 256 + lane * 4);
    f32x4 e10 = *reinterpret_cast<const f32x4*>(r1 + lane * 4);
    f32x4 e11 = *reinterpret_cast<const f32x4*>(r1 + 256 + lane * 4);
    float d0 = e00.x * wa.x + e00.y * wa.y + e00.z * wa.z + e00.w * wa.w
             + e01.x * wb.x + e01.y * wb.y + e01.z * wb.z + e01.w * wb.w;
    float d1 = e10.x * wa.x + e10.y * wa.y + e10.z * wa.z + e10.w * wa.w
             + e11.x * wb.x + e11.y * wb.y + e11.z * wb.z + e11.w * wb.w;
#pragma unroll
    for (int off = 32; off; off >>= 1) {
      d0 += __shfl_xor(d0, off);
      d1 += __shfl_xor(d1, off);
    }
    float mn0 = fmaxf(m0, d0), mn1 = fmaxf(m1, d1);
    float s0 = expf(m0 - mn0), s1 = expf(m1 - mn1);
    float p0 = expf(d0 - mn0), p1 = expf(d1 - mn1);
    l0 = l0 * s0 + p0;         l1 = l1 * s1 + p1;
    a00 = a00 * s0 + p0 * e00; a01 = a01 * s0 + p0 * e01;
    a10 = a10 * s1 + p1 * e10; a11 = a11 * s1 + p1 * e11;
    m0 = mn0; m1 = mn1;
  }
  const float Mw = fmaxf(m0, m1);
  const float c0 = expf(m0 - Mw), c1 = expf(m1 - Mw);
  const float lw = l0 * c0 + l1 * c1;
  const f32x4 accA = a00 * c0 + a10 * c1;
  const f32x4 accB = a01 * c0 + a11 * c1;
  __shared__ float sm[4], sl[4], sacc[4][NH];
  if (lane == 0) { sm[wv] = Mw; sl[wv] = lw; }
  *reinterpret_cast<f32x4*>(&sacc[wv][lane * 4]) = accA;
  *reinterpret_cast<f32x4*>(&sacc[wv][256 + lane * 4]) = accB;
  __syncthreads();
  const float M = fmaxf(fmaxf(sm[0], sm[1]), fmaxf(sm[2], sm[3]));
  const float e0 = expf(sm[0] - M), e1 = expf(sm[1] - M),
              e2 = expf(sm[2] - M), e3 = expf(sm[3] - M);
  const int t = threadIdx.x;
  float* outc = pctx + ((size_t)b * NSC + sc) * NH;
#pragma unroll
  for (int q = 0; q < 2; ++q) {
    int h = q * 256 + t;
    outc[h] = sacc[0][h] * e0 + sacc[1][h] * e1 + sacc[2][h] * e2 + sacc[3][h] * e3;
  }
  if (t == 0) {
    pml[((size_t)b * NSC + sc) * 2 + 0] = M;
    pml[((size_t)b * NSC + sc) * 2 + 1] = sl[0] * e0 + sl[1] * e1 + sl[2] * e2 + sl[3] * e3;
  }
}

// -------- merge partials, emit bf16 x (+embedding) + bf16 hidden copies --
__global__ __launch_bounds__(256) void attn_finish_k(
    const float* __restrict__ pctx, const float* __restrict__ pml,
    const float* __restrict__ emb, const int* __restrict__ dec,
    const float* __restrict__ hidden,
    __hip_bfloat16* __restrict__ xbf,
    __hip_bfloat16* __restrict__ h0bf, __hip_bfloat16* __restrict__ h1bf) {
  const int b = blockIdx.x, t = threadIdx.x;
  float ms[NSC];
  float M = -INFINITY;
#pragma unroll
  for (int sc = 0; sc < NSC; ++sc) {
    ms[sc] = pml[((size_t)b * NSC + sc) * 2 + 0];
    M = fmaxf(M, ms[sc]);
  }
  float L = 0.f, es[NSC];
#pragma unroll
  for (int sc = 0; sc < NSC; ++sc) {
    es[sc] = expf(ms[sc] - M);
    L += pml[((size_t)b * NSC + sc) * 2 + 1] * es[sc];
  }
  const float invL = 1.f / L;
#pragma unroll
  for (int q = 0; q < 2; ++q) {
    int h = q * 256 + t;
    float v = 0.f;
#pragma unroll
    for (int sc = 0; sc < NSC; ++sc)
      v += pctx[((size_t)b * NSC + sc) * NH + h] * es[sc];
    xbf[(size_t)b * NX + h] = __float2bfloat16(v * invL);
    h0bf[(size_t)b * NH + h] = __float2bfloat16(hidden[(size_t)b * NH + h]);
    h1bf[(size_t)b * NH + h] =
        __float2bfloat16(hidden[(size_t)(NB * NH) + (size_t)b * NH + h]);
  }
  xbf[(size_t)b * NX + NH + t] = __float2bfloat16(emb[(size_t)dec[b] * NE + t]);
}

// -------- fused LSTM layer: A-in-registers pipelined GEMM + pointwise ----
// Template KX (x-operand K = stride). Grid (128, 2): block (p, mh) owns
// gate rows {g*512 + p*4 + r} x M rows [mh*64, +64). A fragments preloaded
// to registers (FC recipe); inner loop = LDS weights + MFMA only. Weight
// staging: double-buffered bf16 LDS panels, coalesced f32x4 loads.
constexpr int LSLAB = 520;
template <int KX>
__global__ __launch_bounds__(256, 1) void lstm_fused_k(
    const float* __restrict__ Wx, const float* __restrict__ Wh,
    const __hip_bfloat16* __restrict__ Ax, const __hip_bfloat16* __restrict__ Ah,
    const float* __restrict__ b_ih, const float* __restrict__ b_hh,
    const float* __restrict__ c_in,
    float* __restrict__ h_out, float* __restrict__ c_out,
    __hip_bfloat16* __restrict__ hbf_out) {
  constexpr int NCHX = KX / 256;         // x-chunks
  constexpr int NCH = NCHX + 2;          // + h-chunks
  constexpr int NKS = NCH * 8;           // total 32-wide k-slots
  __shared__ short wlds[2][8 * LSLAB];
  __shared__ float sg[64][17];
  const int tid = threadIdx.x, wv = tid >> 6, lane = tid & 63;
  const int l15 = lane & 15, lhi = lane >> 4;
  const int p = blockIdx.x, mh = blockIdx.y;
  const int srow = tid >> 6;
  const int scol = lane * 4;
  const int soff0 = (scol >> 5) * LSLAB + (scol & 31);

  // ---- preload A fragments for this wave's 16 M rows
  const int arow = mh * 64 + wv * 16 + l15;
  short8 af[NKS];
#pragma unroll
  for (int ks = 0; ks < KX / 32; ++ks)
    af[ks] = *reinterpret_cast<const short8*>(Ax + (size_t)arow * KX + ks * 32 + lhi * 8);
#pragma unroll
  for (int ks = 0; ks < 16; ++ks)
    af[KX / 32 + ks] =
        *reinterpret_cast<const short8*>(Ah + (size_t)arow * NH + ks * 32 + lhi * 8);

  f32x4 wr[4];
#define LSTAGE_LOAD(c)                                                        \
  {                                                                           \
    const bool fx = (c) < NCHX;                                               \
    const float* Ws = fx ? Wx : Wh;                                           \
    const int Ks = fx ? KX : NH;                                              \
    const int cb = fx ? (c) * 256 : ((c) - NCHX) * 256;                       \
    _Pragma("unroll")                                                         \
    for (int i = 0; i < 4; ++i)                                               \
      wr[i] = *reinterpret_cast<const f32x4*>(                                \
          Ws + (size_t)(i * NH + p * 4 + srow) * Ks + cb + scol);             \
  }
#define LSTAGE_WRITE(buf)                                                     \
  {                                                                           \
    _Pragma("unroll")                                                         \
    for (int i = 0; i < 4; ++i) {                                             \
      short4v cv;                                                             \
      cv[0] = bf16s(wr[i].x); cv[1] = bf16s(wr[i].y);                         \
      cv[2] = bf16s(wr[i].z); cv[3] = bf16s(wr[i].w);                         \
      *reinterpret_cast<short4v*>((buf) + soff0 + (i * 4 + srow) * 32) = cv;  \
    }                                                                         \
  }

  LSTAGE_LOAD(0);
  LSTAGE_WRITE(wlds[0]);
  __syncthreads();

  f32x4 acc = {};
#pragma unroll
  for (int c = 0; c < NCH; ++c) {
    if (c + 1 < NCH) LSTAGE_LOAD(c + 1);
    {
      const short* wb = wlds[c & 1];
#pragma unroll
      for (int ks = 0; ks < 8; ++ks) {
        short8 bf = *reinterpret_cast<const short8*>(wb + ks * LSLAB + l15 * 32 + lhi * 8);
        acc = __builtin_amdgcn_mfma_f32_16x16x32_bf16(af[c * 8 + ks], bf, acc, 0, 0, 0);
      }
    }
    if (c + 1 < NCH) {
      LSTAGE_WRITE(wlds[(c + 1) & 1]);
      __syncthreads();
    }
  }
#pragma unroll
  for (int q = 0; q < 4; ++q)
    sg[wv * 16 + lhi * 4 + q][l15] = acc[q];
  __syncthreads();
  {
    const int bl = tid >> 2, r = tid & 3;      // 64 b-rows x 4 h
    const int b = mh * 64 + bl;
    const int h = p * 4 + r;
    float ig = sg[bl][0 + r]  + b_ih[0 * NH + h] + b_hh[0 * NH + h];
    float fg = sg[bl][4 + r]  + b_ih[1 * NH + h] + b_hh[1 * NH + h];
    float gg = sg[bl][8 + r]  + b_ih[2 * NH + h] + b_hh[2 * NH + h];
    float og = sg[bl][12 + r] + b_ih[3 * NH + h] + b_hh[3 * NH + h];
    float c = c_in[(size_t)b * NH + h];
    float c2 = sigf(fg) * c + sigf(ig) * tanhf(gg);
    float h2 = sigf(og) * tanhf(c2);
    c_out[(size_t)b * NH + h] = c2;
    h_out[(size_t)b * NH + h] = h2;
    hbf_out[(size_t)b * NH + h] = __float2bfloat16(h2);
  }
#undef LSTAGE_LOAD
#undef LSTAGE_WRITE
}

// -------- FC: pipelined persistent-panel GEMM (r15-proven, 8 panels) -----
constexpr int FC_PANELS = 8;
constexpr int FC_BLOCKS = NV / (16 * FC_PANELS);   // 250
constexpr int SLAB = 520;                          // shorts per ks slab

__global__ __launch_bounds__(256, 1) void gemm_fc_pipe_k(
    const __hip_bfloat16* __restrict__ Abf, const float* __restrict__ W,
    const float* __restrict__ bias, float* __restrict__ out) {
  __shared__ short wlds[2][16 * SLAB];   // ~16.3 KB per buffer
  const int tid = threadIdx.x, wv = tid >> 6, lane = tid & 63;
  const int l15 = lane & 15, lhi = lane >> 4;
  const int nbase = blockIdx.x * (16 * FC_PANELS);

  int soff[8];
#pragma unroll
  for (int i = 0; i < 8; ++i) {
    const int o = i * 1024 + tid * 4;
    const int n = o >> 9, kk = o & 511;
    soff[i] = (kk >> 5) * SLAB + n * 32 + (kk & 31);
  }

  short8 af[2][16];
#pragma unroll
  for (int m = 0; m < 2; ++m) {
    const __hip_bfloat16* ar = Abf + (size_t)(wv * 32 + m * 16 + l15) * NH + lhi * 8;
#pragma unroll
    for (int ks = 0; ks < 16; ++ks)
      af[m][ks] = *reinterpret_cast<const short8*>(ar + ks * 32);
  }

  f32x4 wr[8];
  {
    const float* panel = W + (size_t)nbase * NH;
#pragma unroll
    for (int i = 0; i < 8; ++i)
      wr[i] = *reinterpret_cast<const f32x4*>(panel + i * 1024 + tid * 4);
    short* wb0 = wlds[0];
#pragma unroll
    for (int i = 0; i < 8; ++i) {
      short4v cv;
      cv[0] = bf16s(wr[i].x); cv[1] = bf16s(wr[i].y);
      cv[2] = bf16s(wr[i].z); cv[3] = bf16s(wr[i].w);
      *reinterpret_cast<short4v*>(wb0 + soff[i]) = cv;
    }
  }
  __syncthreads();

  f32x4 s0 = {}, s1 = {};
  int sn0 = -1;
  for (int p = 0; p < FC_PANELS; ++p) {
    if (p < FC_PANELS - 1) {
      const float* panel = W + (size_t)(nbase + (p + 1) * 16) * NH;
#pragma unroll
      for (int i = 0; i < 8; ++i)
        wr[i] = *reinterpret_cast<const f32x4*>(panel + i * 1024 + tid * 4);
    }
    if (sn0 >= 0) {
      const float bv = bias[sn0 + l15];
#pragma unroll
      for (int q = 0; q < 4; ++q) {
        out[(size_t)(wv * 32 + 0 * 16 + lhi * 4 + q) * NV + sn0 + l15] = s0[q] + bv;
        out[(size_t)(wv * 32 + 1 * 16 + lhi * 4 + q) * NV + sn0 + l15] = s1[q] + bv;
      }
    }
    {
      const short* wb = wlds[p & 1];
      f32x4 a0 = {}, a1 = {};
#pragma unroll
      for (int ks = 0; ks < 16; ++ks) {
        short8 bf = *reinterpret_cast<const short8*>(wb + ks * SLAB + l15 * 32 + lhi * 8);
        a0 = __builtin_amdgcn_mfma_f32_16x16x32_bf16(af[0][ks], bf, a0, 0, 0, 0);
        a1 = __builtin_amdgcn_mfma_f32_16x16x32_bf16(af[1][ks], bf, a1, 0, 0, 0);
      }
      s0 = a0; s1 = a1; sn0 = nbase + p * 16;
    }
    if (p < FC_PANELS - 1) {
      short* wbn = wlds[(p + 1) & 1];
#pragma unroll
      for (int i = 0; i < 8; ++i) {
        short4v cv;
        cv[0] = bf16s(wr[i].x); cv[1] = bf16s(wr[i].y);
        cv[2] = bf16s(wr[i].z); cv[3] = bf16s(wr[i].w);
        *reinterpret_cast<short4v*>(wbn + soff[i]) = cv;
      }
      __syncthreads();
    }
  }
  {
    const float bv = bias[sn0 + l15];
#pragma unroll
    for (int q = 0; q < 4; ++q) {
      out[(size_t)(wv * 32 + 0 * 16 + lhi * 4 + q) * NV + sn0 + l15] = s0[q] + bv;
      out[(size_t)(wv * 32 + 1 * 16 + lhi * 4 + q) * NV + sn0 + l15] = s1[q] + bv;
    }
  }
}

extern "C" void kernel_launch(void* const* d_in, const int* in_sizes, int n_in,
                              void* d_out, int out_size, void* d_ws, size_t ws_size,
                              hipStream_t stream) {
  const int*   dec    = (const int*)d_in[0];
  const float* hidden = (const float*)d_in[1];
  const float* cell   = (const float*)d_in[2];
  const float* enc    = (const float*)d_in[3];
  const float* emb    = (const float*)d_in[4];
  const float* attn_w = (const float*)d_in[5];
  // d_in[6] = attn_b (cancels in softmax)
  const float* w_ih0  = (const float*)d_in[7];
  const float* w_hh0  = (const float*)d_in[8];
  const float* b_ih0  = (const float*)d_in[9];
  const float* b_hh0  = (const float*)d_in[10];
  const float* w_ih1  = (const float*)d_in[11];
  const float* w_hh1  = (const float*)d_in[12];
  const float* b_ih1  = (const float*)d_in[13];
  const float* b_hh1  = (const float*)d_in[14];
  const float* fc_w   = (const float*)d_in[15];
  const float* fc_b   = (const float*)d_in[16];
  float* out = (float*)d_out;
  float* ws  = (float*)d_ws;

  float* pctx = ws + OFF_PCTX;
  float* pml  = ws + OFF_PML;
  __hip_bfloat16* xbf   = (__hip_bfloat16*)(ws + OFF_XBF);
  __hip_bfloat16* h0nbf = (__hip_bfloat16*)(ws + OFF_H0NBF);
  __hip_bfloat16* h1nbf = (__hip_bfloat16*)(ws + OFF_H1NBF);
  __hip_bfloat16* h0bf  = (__hip_bfloat16*)(ws + OFF_H0BFI);
  __hip_bfloat16* h1bf  = (__hip_bfloat16*)(ws + OFF_H1BFI);

  attn_partial_k<<<dim3(NSC, NB), 256, 0, stream>>>(enc, attn_w, pctx, pml);
  attn_finish_k<<<NB, 256, 0, stream>>>(pctx, pml, emb, dec, hidden,
                                        xbf, h0bf, h1bf);
  lstm_fused_k<NX><<<dim3(NH / 4, 2), 256, 0, stream>>>(
      w_ih0, w_hh0, xbf, h0bf, b_ih0, b_hh0, cell,
      out + OUT_HID, out + OUT_CELL, h0nbf);
  lstm_fused_k<NH><<<dim3(NH / 4, 2), 256, 0, stream>>>(
      w_ih1, w_hh1, h0nbf, h1bf, b_ih1, b_hh1, cell + NB * NH,
      out + OUT_HID + (size_t)NB * NH,
      out + OUT_CELL + (size_t)NB * NH, h1nbf);
  gemm_fc_pipe_k<<<FC_BLOCKS, 256, 0, stream>>>(h1nbf, fc_w, fc_b, out);
}

// Round 23
// 66.398 us; speedup vs baseline: 2.0222x; 1.0186x over previous
//
#include <hip/hip_runtime.h>
#include <hip/hip_bf16.h>
#include <math.h>

constexpr int NV = 32000;
constexpr int NE = 256;
constexpr int NH = 512;
constexpr int NB = 128;
constexpr int NS = 512;
constexpr int NX = NH + NE;   // 768, LSTM0 input dim
constexpr int NSC = 8;        // s-chunks for attention partials

typedef __attribute__((ext_vector_type(8))) short short8;   // bf16x8 frag
typedef __attribute__((ext_vector_type(4))) short short4v;  // bf16x4
typedef __attribute__((ext_vector_type(4))) float f32x4;

// -------- workspace layout (float offsets) --------
constexpr size_t OFF_PCTX  = 0;                               // 524288
constexpr size_t OFF_PML   = OFF_PCTX  + (size_t)NB*NSC*NH;   // 2048
constexpr size_t OFF_XBF   = OFF_PML   + (size_t)NB*NSC*2;    // bf16 [128][768]
constexpr size_t OFF_H0NBF = OFF_XBF   + 49152;               // bf16 [128][512]
constexpr size_t OFF_H1NBF = OFF_H0NBF + 32768;
constexpr size_t OFF_H0BFI = OFF_H1NBF + 32768;               // bf16 copy of hidden[0]
constexpr size_t OFF_H1BFI = OFF_H0BFI + 32768;               // bf16 copy of hidden[1]

// d_out layout: pred[128*32000] | new_hidden[2*128*512] | new_cell[2*128*512]
constexpr size_t OUT_HID  = (size_t)NB * NV;
constexpr size_t OUT_CELL = OUT_HID + 2ull * NB * NH;

__device__ inline float sigf(float x) { return 1.0f / (1.0f + expf(-x)); }
__device__ inline short bf16s(float x) {
  __hip_bfloat16 h = __float2bfloat16(x);
  return *reinterpret_cast<short*>(&h);
}

// -------- one-pass online-softmax attention partial, dual chain (r7) -----
__global__ __launch_bounds__(256) void attn_partial_k(
    const float* __restrict__ enc, const float* __restrict__ attn_w,
    float* __restrict__ pctx, float* __restrict__ pml) {
  const int sc = blockIdx.x, b = blockIdx.y;
  const int wv = threadIdx.x >> 6, lane = threadIdx.x & 63;
  const f32x4 wa = *reinterpret_cast<const f32x4*>(attn_w + lane * 4);
  const f32x4 wb = *reinterpret_cast<const f32x4*>(attn_w + 256 + lane * 4);
  float m0 = -INFINITY, l0 = 0.f, m1 = -INFINITY, l1 = 0.f;
  f32x4 a00 = {}, a01 = {}, a10 = {}, a11 = {};
  const float* base = enc + ((size_t)(sc * 64 + wv) * NB + b) * NH;
  for (int i = 0; i < 8; ++i) {
    const float* r0 = base + (size_t)(i * 4) * NB * NH;
    const float* r1 = base + (size_t)((i + 8) * 4) * NB * NH;
    f32x4 e00 = *reinterpret_cast<const f32x4*>(r0 + lane * 4);
    f32x4 e01 = *reinterpret_cast<const f32x4*>(r0 + 256 + lane * 4);
    f32x4 e10 = *reinterpret_cast<const f32x4*>(r1 + lane * 4);
    f32x4 e11 = *reinterpret_cast<const f32x4*>(r1 + 256 + lane * 4);
    float d0 = e00.x * wa.x + e00.y * wa.y + e00.z * wa.z + e00.w * wa.w
             + e01.x * wb.x + e01.y * wb.y + e01.z * wb.z + e01.w * wb.w;
    float d1 = e10.x * wa.x + e10.y * wa.y + e10.z * wa.z + e10.w * wa.w
             + e11.x * wb.x + e11.y * wb.y + e11.z * wb.z + e11.w * wb.w;
#pragma unroll
    for (int off = 32; off; off >>= 1) {
      d0 += __shfl_xor(d0, off);
      d1 += __shfl_xor(d1, off);
    }
    float mn0 = fmaxf(m0, d0), mn1 = fmaxf(m1, d1);
    float s0 = expf(m0 - mn0), s1 = expf(m1 - mn1);
    float p0 = expf(d0 - mn0), p1 = expf(d1 - mn1);
    l0 = l0 * s0 + p0;         l1 = l1 * s1 + p1;
    a00 = a00 * s0 + p0 * e00; a01 = a01 * s0 + p0 * e01;
    a10 = a10 * s1 + p1 * e10; a11 = a11 * s1 + p1 * e11;
    m0 = mn0; m1 = mn1;
  }
  const float Mw = fmaxf(m0, m1);
  const float c0 = expf(m0 - Mw), c1 = expf(m1 - Mw);
  const float lw = l0 * c0 + l1 * c1;
  const f32x4 accA = a00 * c0 + a10 * c1;
  const f32x4 accB = a01 * c0 + a11 * c1;
  __shared__ float sm[4], sl[4], sacc[4][NH];
  if (lane == 0) { sm[wv] = Mw; sl[wv] = lw; }
  *reinterpret_cast<f32x4*>(&sacc[wv][lane * 4]) = accA;
  *reinterpret_cast<f32x4*>(&sacc[wv][256 + lane * 4]) = accB;
  __syncthreads();
  const float M = fmaxf(fmaxf(sm[0], sm[1]), fmaxf(sm[2], sm[3]));
  const float e0 = expf(sm[0] - M), e1 = expf(sm[1] - M),
              e2 = expf(sm[2] - M), e3 = expf(sm[3] - M);
  const int t = threadIdx.x;
  float* outc = pctx + ((size_t)b * NSC + sc) * NH;
#pragma unroll
  for (int q = 0; q < 2; ++q) {
    int h = q * 256 + t;
    outc[h] = sacc[0][h] * e0 + sacc[1][h] * e1 + sacc[2][h] * e2 + sacc[3][h] * e3;
  }
  if (t == 0) {
    pml[((size_t)b * NSC + sc) * 2 + 0] = M;
    pml[((size_t)b * NSC + sc) * 2 + 1] = sl[0] * e0 + sl[1] * e1 + sl[2] * e2 + sl[3] * e3;
  }
}

// -------- merge partials, emit bf16 x (+embedding) + bf16 hidden copies --
__global__ __launch_bounds__(256) void attn_finish_k(
    const float* __restrict__ pctx, const float* __restrict__ pml,
    const float* __restrict__ emb, const int* __restrict__ dec,
    const float* __restrict__ hidden,
    __hip_bfloat16* __restrict__ xbf,
    __hip_bfloat16* __restrict__ h0bf, __hip_bfloat16* __restrict__ h1bf) {
  const int b = blockIdx.x, t = threadIdx.x;
  float ms[NSC];
  float M = -INFINITY;
#pragma unroll
  for (int sc = 0; sc < NSC; ++sc) {
    ms[sc] = pml[((size_t)b * NSC + sc) * 2 + 0];
    M = fmaxf(M, ms[sc]);
  }
  float L = 0.f, es[NSC];
#pragma unroll
  for (int sc = 0; sc < NSC; ++sc) {
    es[sc] = expf(ms[sc] - M);
    L += pml[((size_t)b * NSC + sc) * 2 + 1] * es[sc];
  }
  const float invL = 1.f / L;
#pragma unroll
  for (int q = 0; q < 2; ++q) {
    int h = q * 256 + t;
    float v = 0.f;
#pragma unroll
    for (int sc = 0; sc < NSC; ++sc)
      v += pctx[((size_t)b * NSC + sc) * NH + h] * es[sc];
    xbf[(size_t)b * NX + h] = __float2bfloat16(v * invL);
    h0bf[(size_t)b * NH + h] = __float2bfloat16(hidden[(size_t)b * NH + h]);
    h1bf[(size_t)b * NH + h] =
        __float2bfloat16(hidden[(size_t)(NB * NH) + (size_t)b * NH + h]);
  }
  xbf[(size_t)b * NX + NH + t] = __float2bfloat16(emb[(size_t)dec[b] * NE + t]);
}

// -------- fused LSTM layer v3: streamed-A, 2 blocks/CU ----
// Template KX. Grid (4 mh, 128 p), 128 threads (2 waves). Block (mh,p) owns
// gate rows {g*512 + p*4 + rr : g<4, rr<4} x M rows [mh*32, +32).
// A streamed per-chunk into double-buffered registers afbuf[2][8] (static
// indices after unroll); weights double-buffered bf16 in LDS. 512 blocks
// = 2/CU so co-resident blocks hide each other's barrier/load stalls.
constexpr int LSLAB = 520;
template <int KX>
__global__ __launch_bounds__(128, 2) void lstm_fused_k(
    const float* __restrict__ Wx, const float* __restrict__ Wh,
    const __hip_bfloat16* __restrict__ Ax, const __hip_bfloat16* __restrict__ Ah,
    const float* __restrict__ b_ih, const float* __restrict__ b_hh,
    const float* __restrict__ c_in,
    float* __restrict__ h_out, float* __restrict__ c_out,
    __hip_bfloat16* __restrict__ hbf_out) {
  constexpr int NCHX = KX / 256;         // x-chunks
  constexpr int NCH = NCHX + 2;          // + h-chunks
  __shared__ short wlds[2][8 * LSLAB];
  __shared__ float sg[32][17];
  const int tid = threadIdx.x, wv = tid >> 6, lane = tid & 63;
  const int l15 = lane & 15, lhi = lane >> 4;
  const int mh = blockIdx.x, p = blockIdx.y;
  const int srow = tid >> 6;             // 0..1
  const int scol = lane * 4;             // 0..252
  const int soff0 = (scol >> 5) * LSLAB + (scol & 31);
  const int arow = mh * 32 + wv * 16 + l15;   // this thread's A row

  short8 afbuf[2][8];
  f32x4 wr[8];

#define A_LOAD(c, buf)                                                        \
  {                                                                           \
    const __hip_bfloat16* ab =                                                \
        ((c) < NCHX) ? (Ax + (size_t)arow * KX + (c) * 256 + lhi * 8)         \
                     : (Ah + (size_t)arow * NH + ((c) - NCHX) * 256 + lhi * 8);\
    _Pragma("unroll")                                                         \
    for (int ks = 0; ks < 8; ++ks)                                            \
      (buf)[ks] = *reinterpret_cast<const short8*>(ab + ks * 32);             \
  }
#define LSTAGE_LOAD(c)                                                        \
  {                                                                           \
    const bool fx = (c) < NCHX;                                               \
    const float* Ws = fx ? Wx : Wh;                                           \
    const int Ks = fx ? KX : NH;                                              \
    const int cb = fx ? (c) * 256 : ((c) - NCHX) * 256;                       \
    _Pragma("unroll")                                                         \
    for (int i = 0; i < 8; ++i) {                                             \
      const int j = i * 2 + srow;                                             \
      const int g = j >> 2, rr = j & 3;                                       \
      wr[i] = *reinterpret_cast<const f32x4*>(                                \
          Ws + (size_t)(g * NH + p * 4 + rr) * Ks + cb + scol);               \
    }                                                                         \
  }
#define LSTAGE_WRITE(buf)                                                     \
  {                                                                           \
    _Pragma("unroll")                                                         \
    for (int i = 0; i < 8; ++i) {                                             \
      const int j = i * 2 + srow;                                             \
      short4v cv;                                                             \
      cv[0] = bf16s(wr[i].x); cv[1] = bf16s(wr[i].y);                         \
      cv[2] = bf16s(wr[i].z); cv[3] = bf16s(wr[i].w);                         \
      *reinterpret_cast<short4v*>((buf) + soff0 + j * 32) = cv;               \
    }                                                                         \
  }

  A_LOAD(0, afbuf[0]);
  LSTAGE_LOAD(0);
  LSTAGE_WRITE(wlds[0]);
  __syncthreads();

  f32x4 acc = {};
#pragma unroll
  for (int c = 0; c < NCH; ++c) {
    if (c + 1 < NCH) {
      LSTAGE_LOAD(c + 1);
      A_LOAD(c + 1, afbuf[(c + 1) & 1]);
    }
    {
      const short* wb = wlds[c & 1];
#pragma unroll
      for (int ks = 0; ks < 8; ++ks) {
        short8 bf = *reinterpret_cast<const short8*>(wb + ks * LSLAB + l15 * 32 + lhi * 8);
        acc = __builtin_amdgcn_mfma_f32_16x16x32_bf16(afbuf[c & 1][ks], bf, acc, 0, 0, 0);
      }
    }
    if (c + 1 < NCH) {
      LSTAGE_WRITE(wlds[(c + 1) & 1]);
      __syncthreads();
    }
  }
#pragma unroll
  for (int q = 0; q < 4; ++q)
    sg[wv * 16 + lhi * 4 + q][l15] = acc[q];
  __syncthreads();
  {
    const int bl = tid >> 2, r = tid & 3;      // 32 b-rows x 4 h
    const int b = mh * 32 + bl;
    const int h = p * 4 + r;
    float ig = sg[bl][0 + r]  + b_ih[0 * NH + h] + b_hh[0 * NH + h];
    float fg = sg[bl][4 + r]  + b_ih[1 * NH + h] + b_hh[1 * NH + h];
    float gg = sg[bl][8 + r]  + b_ih[2 * NH + h] + b_hh[2 * NH + h];
    float og = sg[bl][12 + r] + b_ih[3 * NH + h] + b_hh[3 * NH + h];
    float c = c_in[(size_t)b * NH + h];
    float c2 = sigf(fg) * c + sigf(ig) * tanhf(gg);
    float h2 = sigf(og) * tanhf(c2);
    c_out[(size_t)b * NH + h] = c2;
    h_out[(size_t)b * NH + h] = h2;
    hbf_out[(size_t)b * NH + h] = __float2bfloat16(h2);
  }
#undef A_LOAD
#undef LSTAGE_LOAD
#undef LSTAGE_WRITE
}

// -------- FC: pipelined persistent-panel GEMM (r15-proven, 8 panels) -----
constexpr int FC_PANELS = 8;
constexpr int FC_BLOCKS = NV / (16 * FC_PANELS);   // 250
constexpr int SLAB = 520;                          // shorts per ks slab

__global__ __launch_bounds__(256, 1) void gemm_fc_pipe_k(
    const __hip_bfloat16* __restrict__ Abf, const float* __restrict__ W,
    const float* __restrict__ bias, float* __restrict__ out) {
  __shared__ short wlds[2][16 * SLAB];   // ~16.3 KB per buffer
  const int tid = threadIdx.x, wv = tid >> 6, lane = tid & 63;
  const int l15 = lane & 15, lhi = lane >> 4;
  const int nbase = blockIdx.x * (16 * FC_PANELS);

  int soff[8];
#pragma unroll
  for (int i = 0; i < 8; ++i) {
    const int o = i * 1024 + tid * 4;
    const int n = o >> 9, kk = o & 511;
    soff[i] = (kk >> 5) * SLAB + n * 32 + (kk & 31);
  }

  short8 af[2][16];
#pragma unroll
  for (int m = 0; m < 2; ++m) {
    const __hip_bfloat16* ar = Abf + (size_t)(wv * 32 + m * 16 + l15) * NH + lhi * 8;
#pragma unroll
    for (int ks = 0; ks < 16; ++ks)
      af[m][ks] = *reinterpret_cast<const short8*>(ar + ks * 32);
  }

  f32x4 wr[8];
  {
    const float* panel = W + (size_t)nbase * NH;
#pragma unroll
    for (int i = 0; i < 8; ++i)
      wr[i] = *reinterpret_cast<const f32x4*>(panel + i * 1024 + tid * 4);
    short* wb0 = wlds[0];
#pragma unroll
    for (int i = 0; i < 8; ++i) {
      short4v cv;
      cv[0] = bf16s(wr[i].x); cv[1] = bf16s(wr[i].y);
      cv[2] = bf16s(wr[i].z); cv[3] = bf16s(wr[i].w);
      *reinterpret_cast<short4v*>(wb0 + soff[i]) = cv;
    }
  }
  __syncthreads();

  f32x4 s0 = {}, s1 = {};
  int sn0 = -1;
  for (int p = 0; p < FC_PANELS; ++p) {
    if (p < FC_PANELS - 1) {
      const float* panel = W + (size_t)(nbase + (p + 1) * 16) * NH;
#pragma unroll
      for (int i = 0; i < 8; ++i)
        wr[i] = *reinterpret_cast<const f32x4*>(panel + i * 1024 + tid * 4);
    }
    if (sn0 >= 0) {
      const float bv = bias[sn0 + l15];
#pragma unroll
      for (int q = 0; q < 4; ++q) {
        out[(size_t)(wv * 32 + 0 * 16 + lhi * 4 + q) * NV + sn0 + l15] = s0[q] + bv;
        out[(size_t)(wv * 32 + 1 * 16 + lhi * 4 + q) * NV + sn0 + l15] = s1[q] + bv;
      }
    }
    {
      const short* wb = wlds[p & 1];
      f32x4 a0 = {}, a1 = {};
#pragma unroll
      for (int ks = 0; ks < 16; ++ks) {
        short8 bf = *reinterpret_cast<const short8*>(wb + ks * SLAB + l15 * 32 + lhi * 8);
        a0 = __builtin_amdgcn_mfma_f32_16x16x32_bf16(af[0][ks], bf, a0, 0, 0, 0);
        a1 = __builtin_amdgcn_mfma_f32_16x16x32_bf16(af[1][ks], bf, a1, 0, 0, 0);
      }
      s0 = a0; s1 = a1; sn0 = nbase + p * 16;
    }
    if (p < FC_PANELS - 1) {
      short* wbn = wlds[(p + 1) & 1];
#pragma unroll
      for (int i = 0; i < 8; ++i) {
        short4v cv;
        cv[0] = bf16s(wr[i].x); cv[1] = bf16s(wr[i].y);
        cv[2] = bf16s(wr[i].z); cv[3] = bf16s(wr[i].w);
        *reinterpret_cast<short4v*>(wbn + soff[i]) = cv;
      }
      __syncthreads();
    }
  }
  {
    const float bv = bias[sn0 + l15];
#pragma unroll
    for (int q = 0; q < 4; ++q) {
      out[(size_t)(wv * 32 + 0 * 16 + lhi * 4 + q) * NV + sn0 + l15] = s0[q] + bv;
      out[(size_t)(wv * 32 + 1 * 16 + lhi * 4 + q) * NV + sn0 + l15] = s1[q] + bv;
    }
  }
}

extern "C" void kernel_launch(void* const* d_in, const int* in_sizes, int n_in,
                              void* d_out, int out_size, void* d_ws, size_t ws_size,
                              hipStream_t stream) {
  const int*   dec    = (const int*)d_in[0];
  const float* hidden = (const float*)d_in[1];
  const float* cell   = (const float*)d_in[2];
  const float* enc    = (const float*)d_in[3];
  const float* emb    = (const float*)d_in[4];
  const float* attn_w = (const float*)d_in[5];
  // d_in[6] = attn_b (cancels in softmax)
  const float* w_ih0  = (const float*)d_in[7];
  const float* w_hh0  = (const float*)d_in[8];
  const float* b_ih0  = (const float*)d_in[9];
  const float* b_hh0  = (const float*)d_in[10];
  const float* w_ih1  = (const float*)d_in[11];
  const float* w_hh1  = (const float*)d_in[12];
  const float* b_ih1  = (const float*)d_in[13];
  const float* b_hh1  = (const float*)d_in[14];
  const float* fc_w   = (const float*)d_in[15];
  const float* fc_b   = (const float*)d_in[16];
  float* out = (float*)d_out;
  float* ws  = (float*)d_ws;

  float* pctx = ws + OFF_PCTX;
  float* pml  = ws + OFF_PML;
  __hip_bfloat16* xbf   = (__hip_bfloat16*)(ws + OFF_XBF);
  __hip_bfloat16* h0nbf = (__hip_bfloat16*)(ws + OFF_H0NBF);
  __hip_bfloat16* h1nbf = (__hip_bfloat16*)(ws + OFF_H1NBF);
  __hip_bfloat16* h0bf  = (__hip_bfloat16*)(ws + OFF_H0BFI);
  __hip_bfloat16* h1bf  = (__hip_bfloat16*)(ws + OFF_H1BFI);

  attn_partial_k<<<dim3(NSC, NB), 256, 0, stream>>>(enc, attn_w, pctx, pml);
  attn_finish_k<<<NB, 256, 0, stream>>>(pctx, pml, emb, dec, hidden,
                                        xbf, h0bf, h1bf);
  lstm_fused_k<NX><<<dim3(4, NH / 4), 128, 0, stream>>>(
      w_ih0, w_hh0, xbf, h0bf, b_ih0, b_hh0, cell,
      out + OUT_HID, out + OUT_CELL, h0nbf);
  lstm_fused_k<NH><<<dim3(4, NH / 4), 128, 0, stream>>>(
      w_ih1, w_hh1, h0nbf, h1bf, b_ih1, b_hh1, cell + NB * NH,
      out + OUT_HID + (size_t)NB * NH,
      out + OUT_CELL + (size_t)NB * NH, h1nbf);
  gemm_fc_pipe_k<<<FC_BLOCKS, 256, 0, stream>>>(h1nbf, fc_w, fc_b, out);
}

// Round 24
// 65.561 us; speedup vs baseline: 2.0481x; 1.0128x over previous
//
#include <hip/hip_runtime.h>
#include <hip/hip_bf16.h>
#include <math.h>

constexpr int NV = 32000;
constexpr int NE = 256;
constexpr int NH = 512;
constexpr int NB = 128;
constexpr int NS = 512;
constexpr int NX = NH + NE;   // 768, LSTM0 input dim
constexpr int NSC = 8;        // s-chunks for attention partials

typedef __attribute__((ext_vector_type(8))) short short8;   // bf16x8 frag
typedef __attribute__((ext_vector_type(4))) short short4v;  // bf16x4
typedef __attribute__((ext_vector_type(4))) float f32x4;

// -------- workspace layout (float offsets) --------
constexpr size_t OFF_PCTX  = 0;                               // 524288
constexpr size_t OFF_PML   = OFF_PCTX  + (size_t)NB*NSC*NH;   // 2048
constexpr size_t OFF_XBF   = OFF_PML   + (size_t)NB*NSC*2;    // bf16 [128][768]
constexpr size_t OFF_H0NBF = OFF_XBF   + 49152;               // bf16 [128][512]
constexpr size_t OFF_H1NBF = OFF_H0NBF + 32768;
constexpr size_t OFF_H0BFI = OFF_H1NBF + 32768;               // bf16 copy of hidden[0]
constexpr size_t OFF_H1BFI = OFF_H0BFI + 32768;               // bf16 copy of hidden[1]

// d_out layout: pred[128*32000] | new_hidden[2*128*512] | new_cell[2*128*512]
constexpr size_t OUT_HID  = (size_t)NB * NV;
constexpr size_t OUT_CELL = OUT_HID + 2ull * NB * NH;

__device__ inline float sigf(float x) { return 1.0f / (1.0f + expf(-x)); }
__device__ inline short bf16s(float x) {
  __hip_bfloat16 h = __float2bfloat16(x);
  return *reinterpret_cast<short*>(&h);
}

// -------- one-pass online-softmax attention partial, dual chain (r7) -----
__global__ __launch_bounds__(256) void attn_partial_k(
    const float* __restrict__ enc, const float* __restrict__ attn_w,
    float* __restrict__ pctx, float* __restrict__ pml) {
  const int sc = blockIdx.x, b = blockIdx.y;
  const int wv = threadIdx.x >> 6, lane = threadIdx.x & 63;
  const f32x4 wa = *reinterpret_cast<const f32x4*>(attn_w + lane * 4);
  const f32x4 wb = *reinterpret_cast<const f32x4*>(attn_w + 256 + lane * 4);
  float m0 = -INFINITY, l0 = 0.f, m1 = -INFINITY, l1 = 0.f;
  f32x4 a00 = {}, a01 = {}, a10 = {}, a11 = {};
  const float* base = enc + ((size_t)(sc * 64 + wv) * NB + b) * NH;
  for (int i = 0; i < 8; ++i) {
    const float* r0 = base + (size_t)(i * 4) * NB * NH;
    const float* r1 = base + (size_t)((i + 8) * 4) * NB * NH;
    f32x4 e00 = *reinterpret_cast<const f32x4*>(r0 + lane * 4);
    f32x4 e01 = *reinterpret_cast<const f32x4*>(r0 + 256 + lane * 4);
    f32x4 e10 = *reinterpret_cast<const f32x4*>(r1 + lane * 4);
    f32x4 e11 = *reinterpret_cast<const f32x4*>(r1 + 256 + lane * 4);
    float d0 = e00.x * wa.x + e00.y * wa.y + e00.z * wa.z + e00.w * wa.w
             + e01.x * wb.x + e01.y * wb.y + e01.z * wb.z + e01.w * wb.w;
    float d1 = e10.x * wa.x + e10.y * wa.y + e10.z * wa.z + e10.w * wa.w
             + e11.x * wb.x + e11.y * wb.y + e11.z * wb.z + e11.w * wb.w;
#pragma unroll
    for (int off = 32; off; off >>= 1) {
      d0 += __shfl_xor(d0, off);
      d1 += __shfl_xor(d1, off);
    }
    float mn0 = fmaxf(m0, d0), mn1 = fmaxf(m1, d1);
    float s0 = expf(m0 - mn0), s1 = expf(m1 - mn1);
    float p0 = expf(d0 - mn0), p1 = expf(d1 - mn1);
    l0 = l0 * s0 + p0;         l1 = l1 * s1 + p1;
    a00 = a00 * s0 + p0 * e00; a01 = a01 * s0 + p0 * e01;
    a10 = a10 * s1 + p1 * e10; a11 = a11 * s1 + p1 * e11;
    m0 = mn0; m1 = mn1;
  }
  const float Mw = fmaxf(m0, m1);
  const float c0 = expf(m0 - Mw), c1 = expf(m1 - Mw);
  const float lw = l0 * c0 + l1 * c1;
  const f32x4 accA = a00 * c0 + a10 * c1;
  const f32x4 accB = a01 * c0 + a11 * c1;
  __shared__ float sm[4], sl[4], sacc[4][NH];
  if (lane == 0) { sm[wv] = Mw; sl[wv] = lw; }
  *reinterpret_cast<f32x4*>(&sacc[wv][lane * 4]) = accA;
  *reinterpret_cast<f32x4*>(&sacc[wv][256 + lane * 4]) = accB;
  __syncthreads();
  const float M = fmaxf(fmaxf(sm[0], sm[1]), fmaxf(sm[2], sm[3]));
  const float e0 = expf(sm[0] - M), e1 = expf(sm[1] - M),
              e2 = expf(sm[2] - M), e3 = expf(sm[3] - M);
  const int t = threadIdx.x;
  float* outc = pctx + ((size_t)b * NSC + sc) * NH;
#pragma unroll
  for (int q = 0; q < 2; ++q) {
    int h = q * 256 + t;
    outc[h] = sacc[0][h] * e0 + sacc[1][h] * e1 + sacc[2][h] * e2 + sacc[3][h] * e3;
  }
  if (t == 0) {
    pml[((size_t)b * NSC + sc) * 2 + 0] = M;
    pml[((size_t)b * NSC + sc) * 2 + 1] = sl[0] * e0 + sl[1] * e1 + sl[2] * e2 + sl[3] * e3;
  }
}

// -------- merge partials, emit bf16 x (+embedding) + bf16 hidden copies --
__global__ __launch_bounds__(256) void attn_finish_k(
    const float* __restrict__ pctx, const float* __restrict__ pml,
    const float* __restrict__ emb, const int* __restrict__ dec,
    const float* __restrict__ hidden,
    __hip_bfloat16* __restrict__ xbf,
    __hip_bfloat16* __restrict__ h0bf, __hip_bfloat16* __restrict__ h1bf) {
  const int b = blockIdx.x, t = threadIdx.x;
  float ms[NSC];
  float M = -INFINITY;
#pragma unroll
  for (int sc = 0; sc < NSC; ++sc) {
    ms[sc] = pml[((size_t)b * NSC + sc) * 2 + 0];
    M = fmaxf(M, ms[sc]);
  }
  float L = 0.f, es[NSC];
#pragma unroll
  for (int sc = 0; sc < NSC; ++sc) {
    es[sc] = expf(ms[sc] - M);
    L += pml[((size_t)b * NSC + sc) * 2 + 1] * es[sc];
  }
  const float invL = 1.f / L;
#pragma unroll
  for (int q = 0; q < 2; ++q) {
    int h = q * 256 + t;
    float v = 0.f;
#pragma unroll
    for (int sc = 0; sc < NSC; ++sc)
      v += pctx[((size_t)b * NSC + sc) * NH + h] * es[sc];
    xbf[(size_t)b * NX + h] = __float2bfloat16(v * invL);
    h0bf[(size_t)b * NH + h] = __float2bfloat16(hidden[(size_t)b * NH + h]);
    h1bf[(size_t)b * NH + h] =
        __float2bfloat16(hidden[(size_t)(NB * NH) + (size_t)b * NH + h]);
  }
  xbf[(size_t)b * NX + NH + t] = __float2bfloat16(emb[(size_t)dec[b] * NE + t]);
}

// -------- fused LSTM layer v3 (r23-proven): streamed-A, 2 blocks/CU ------
constexpr int LSLAB = 520;
template <int KX>
__global__ __launch_bounds__(128, 2) void lstm_fused_k(
    const float* __restrict__ Wx, const float* __restrict__ Wh,
    const __hip_bfloat16* __restrict__ Ax, const __hip_bfloat16* __restrict__ Ah,
    const float* __restrict__ b_ih, const float* __restrict__ b_hh,
    const float* __restrict__ c_in,
    float* __restrict__ h_out, float* __restrict__ c_out,
    __hip_bfloat16* __restrict__ hbf_out) {
  constexpr int NCHX = KX / 256;         // x-chunks
  constexpr int NCH = NCHX + 2;          // + h-chunks
  __shared__ short wlds[2][8 * LSLAB];
  __shared__ float sg[32][17];
  const int tid = threadIdx.x, wv = tid >> 6, lane = tid & 63;
  const int l15 = lane & 15, lhi = lane >> 4;
  const int mh = blockIdx.x, p = blockIdx.y;
  const int srow = tid >> 6;             // 0..1
  const int scol = lane * 4;             // 0..252
  const int soff0 = (scol >> 5) * LSLAB + (scol & 31);
  const int arow = mh * 32 + wv * 16 + l15;   // this thread's A row

  short8 afbuf[2][8];
  f32x4 wr[8];

#define A_LOAD(c, buf)                                                        \
  {                                                                           \
    const __hip_bfloat16* ab =                                                \
        ((c) < NCHX) ? (Ax + (size_t)arow * KX + (c) * 256 + lhi * 8)         \
                     : (Ah + (size_t)arow * NH + ((c) - NCHX) * 256 + lhi * 8);\
    _Pragma("unroll")                                                         \
    for (int ks = 0; ks < 8; ++ks)                                            \
      (buf)[ks] = *reinterpret_cast<const short8*>(ab + ks * 32);             \
  }
#define LSTAGE_LOAD(c)                                                        \
  {                                                                           \
    const bool fx = (c) < NCHX;                                               \
    const float* Ws = fx ? Wx : Wh;                                           \
    const int Ks = fx ? KX : NH;                                              \
    const int cb = fx ? (c) * 256 : ((c) - NCHX) * 256;                       \
    _Pragma("unroll")                                                         \
    for (int i = 0; i < 8; ++i) {                                             \
      const int j = i * 2 + srow;                                             \
      const int g = j >> 2, rr = j & 3;                                       \
      wr[i] = *reinterpret_cast<const f32x4*>(                                \
          Ws + (size_t)(g * NH + p * 4 + rr) * Ks + cb + scol);               \
    }                                                                         \
  }
#define LSTAGE_WRITE(buf)                                                     \
  {                                                                           \
    _Pragma("unroll")                                                         \
    for (int i = 0; i < 8; ++i) {                                             \
      const int j = i * 2 + srow;                                             \
      short4v cv;                                                             \
      cv[0] = bf16s(wr[i].x); cv[1] = bf16s(wr[i].y);                         \
      cv[2] = bf16s(wr[i].z); cv[3] = bf16s(wr[i].w);                         \
      *reinterpret_cast<short4v*>((buf) + soff0 + j * 32) = cv;               \
    }                                                                         \
  }

  A_LOAD(0, afbuf[0]);
  LSTAGE_LOAD(0);
  LSTAGE_WRITE(wlds[0]);
  __syncthreads();

  f32x4 acc = {};
#pragma unroll
  for (int c = 0; c < NCH; ++c) {
    if (c + 1 < NCH) {
      LSTAGE_LOAD(c + 1);
      A_LOAD(c + 1, afbuf[(c + 1) & 1]);
    }
    {
      const short* wb = wlds[c & 1];
#pragma unroll
      for (int ks = 0; ks < 8; ++ks) {
        short8 bf = *reinterpret_cast<const short8*>(wb + ks * LSLAB + l15 * 32 + lhi * 8);
        acc = __builtin_amdgcn_mfma_f32_16x16x32_bf16(afbuf[c & 1][ks], bf, acc, 0, 0, 0);
      }
    }
    if (c + 1 < NCH) {
      LSTAGE_WRITE(wlds[(c + 1) & 1]);
      __syncthreads();
    }
  }
#pragma unroll
  for (int q = 0; q < 4; ++q)
    sg[wv * 16 + lhi * 4 + q][l15] = acc[q];
  __syncthreads();
  {
    const int bl = tid >> 2, r = tid & 3;      // 32 b-rows x 4 h
    const int b = mh * 32 + bl;
    const int h = p * 4 + r;
    float ig = sg[bl][0 + r]  + b_ih[0 * NH + h] + b_hh[0 * NH + h];
    float fg = sg[bl][4 + r]  + b_ih[1 * NH + h] + b_hh[1 * NH + h];
    float gg = sg[bl][8 + r]  + b_ih[2 * NH + h] + b_hh[2 * NH + h];
    float og = sg[bl][12 + r] + b_ih[3 * NH + h] + b_hh[3 * NH + h];
    float c = c_in[(size_t)b * NH + h];
    float c2 = sigf(fg) * c + sigf(ig) * tanhf(gg);
    float h2 = sigf(og) * tanhf(c2);
    c_out[(size_t)b * NH + h] = c2;
    h_out[(size_t)b * NH + h] = h2;
    hbf_out[(size_t)b * NH + h] = __float2bfloat16(h2);
  }
#undef A_LOAD
#undef LSTAGE_LOAD
#undef LSTAGE_WRITE
}

// -------- FC: triple-buffered pipelined panel GEMM --------
// 250 blocks x 8 panels. Loads issued TWO panels ahead (double-buffered
// registers wrb[2], triple-buffered LDS wlds[3]) so the convert+ds_write
// never waits on HBM latency. Per iter: issue loads(p+2) -> store out(p-1)
// -> convert+write(p+1) -> compute(p) -> barrier. Loop fully unrolled so
// all buffer indices are compile-time.
constexpr int FC_PANELS = 8;
constexpr int FC_BLOCKS = NV / (16 * FC_PANELS);   // 250
constexpr int SLAB = 520;                          // shorts per ks slab

__global__ __launch_bounds__(256, 1) void gemm_fc_pipe_k(
    const __hip_bfloat16* __restrict__ Abf, const float* __restrict__ W,
    const float* __restrict__ bias, float* __restrict__ out) {
  __shared__ short wlds[3][16 * SLAB];   // ~16.3 KB each
  const int tid = threadIdx.x, wv = tid >> 6, lane = tid & 63;
  const int l15 = lane & 15, lhi = lane >> 4;
  const int nbase = blockIdx.x * (16 * FC_PANELS);

  int soff[8];
#pragma unroll
  for (int i = 0; i < 8; ++i) {
    const int o = i * 1024 + tid * 4;
    const int n = o >> 9, kk = o & 511;
    soff[i] = (kk >> 5) * SLAB + n * 32 + (kk & 31);
  }

  short8 af[2][16];
#pragma unroll
  for (int m = 0; m < 2; ++m) {
    const __hip_bfloat16* ar = Abf + (size_t)(wv * 32 + m * 16 + l15) * NH + lhi * 8;
#pragma unroll
    for (int ks = 0; ks < 16; ++ks)
      af[m][ks] = *reinterpret_cast<const short8*>(ar + ks * 32);
  }

  f32x4 wrb[2][8];
  // ---- prologue: load panels 0 and 1; convert panel 0 into wlds[0]
  {
    const float* p0 = W + (size_t)nbase * NH;
#pragma unroll
    for (int i = 0; i < 8; ++i)
      wrb[0][i] = *reinterpret_cast<const f32x4*>(p0 + i * 1024 + tid * 4);
    const float* p1 = W + (size_t)(nbase + 16) * NH;
#pragma unroll
    for (int i = 0; i < 8; ++i)
      wrb[1][i] = *reinterpret_cast<const f32x4*>(p1 + i * 1024 + tid * 4);
#pragma unroll
    for (int i = 0; i < 8; ++i) {
      short4v cv;
      cv[0] = bf16s(wrb[0][i].x); cv[1] = bf16s(wrb[0][i].y);
      cv[2] = bf16s(wrb[0][i].z); cv[3] = bf16s(wrb[0][i].w);
      *reinterpret_cast<short4v*>(wlds[0] + soff[i]) = cv;
    }
  }
  __syncthreads();

  f32x4 s0 = {}, s1 = {};
  int sn0 = -1;
#pragma unroll
  for (int p = 0; p < FC_PANELS; ++p) {
    // issue loads two panels ahead into the register buffer just freed
    if (p + 2 < FC_PANELS) {
      const float* pan = W + (size_t)(nbase + (p + 2) * 16) * NH;
#pragma unroll
      for (int i = 0; i < 8; ++i)
        wrb[p & 1][i] = *reinterpret_cast<const f32x4*>(pan + i * 1024 + tid * 4);
    }
    // deferred store of previous panel's outputs
    if (sn0 >= 0) {
      const float bv = bias[sn0 + l15];
#pragma unroll
      for (int q = 0; q < 4; ++q) {
        out[(size_t)(wv * 32 + 0 * 16 + lhi * 4 + q) * NV + sn0 + l15] = s0[q] + bv;
        out[(size_t)(wv * 32 + 1 * 16 + lhi * 4 + q) * NV + sn0 + l15] = s1[q] + bv;
      }
    }
    // convert+write panel p+1 (its loads landed an iteration ago)
    if (p + 1 < FC_PANELS) {
      short* dst = wlds[(p + 1) % 3];
#pragma unroll
      for (int i = 0; i < 8; ++i) {
        short4v cv;
        cv[0] = bf16s(wrb[(p + 1) & 1][i].x); cv[1] = bf16s(wrb[(p + 1) & 1][i].y);
        cv[2] = bf16s(wrb[(p + 1) & 1][i].z); cv[3] = bf16s(wrb[(p + 1) & 1][i].w);
        *reinterpret_cast<short4v*>(dst + soff[i]) = cv;
      }
    }
    // compute panel p from LDS
    {
      const short* wb = wlds[p % 3];
      f32x4 a0 = {}, a1 = {};
#pragma unroll
      for (int ks = 0; ks < 16; ++ks) {
        short8 bf = *reinterpret_cast<const short8*>(wb + ks * SLAB + l15 * 32 + lhi * 8);
        a0 = __builtin_amdgcn_mfma_f32_16x16x32_bf16(af[0][ks], bf, a0, 0, 0, 0);
        a1 = __builtin_amdgcn_mfma_f32_16x16x32_bf16(af[1][ks], bf, a1, 0, 0, 0);
      }
      s0 = a0; s1 = a1; sn0 = nbase + p * 16;
    }
    __syncthreads();
  }
  {
    const float bv = bias[sn0 + l15];
#pragma unroll
    for (int q = 0; q < 4; ++q) {
      out[(size_t)(wv * 32 + 0 * 16 + lhi * 4 + q) * NV + sn0 + l15] = s0[q] + bv;
      out[(size_t)(wv * 32 + 1 * 16 + lhi * 4 + q) * NV + sn0 + l15] = s1[q] + bv;
    }
  }
}

extern "C" void kernel_launch(void* const* d_in, const int* in_sizes, int n_in,
                              void* d_out, int out_size, void* d_ws, size_t ws_size,
                              hipStream_t stream) {
  const int*   dec    = (const int*)d_in[0];
  const float* hidden = (const float*)d_in[1];
  const float* cell   = (const float*)d_in[2];
  const float* enc    = (const float*)d_in[3];
  const float* emb    = (const float*)d_in[4];
  const float* attn_w = (const float*)d_in[5];
  // d_in[6] = attn_b (cancels in softmax)
  const float* w_ih0  = (const float*)d_in[7];
  const float* w_hh0  = (const float*)d_in[8];
  const float* b_ih0  = (const float*)d_in[9];
  const float* b_hh0  = (const float*)d_in[10];
  const float* w_ih1  = (const float*)d_in[11];
  const float* w_hh1  = (const float*)d_in[12];
  const float* b_ih1  = (const float*)d_in[13];
  const float* b_hh1  = (const float*)d_in[14];
  const float* fc_w   = (const float*)d_in[15];
  const float* fc_b   = (const float*)d_in[16];
  float* out = (float*)d_out;
  float* ws  = (float*)d_ws;

  float* pctx = ws + OFF_PCTX;
  float* pml  = ws + OFF_PML;
  __hip_bfloat16* xbf   = (__hip_bfloat16*)(ws + OFF_XBF);
  __hip_bfloat16* h0nbf = (__hip_bfloat16*)(ws + OFF_H0NBF);
  __hip_bfloat16* h1nbf = (__hip_bfloat16*)(ws + OFF_H1NBF);
  __hip_bfloat16* h0bf  = (__hip_bfloat16*)(ws + OFF_H0BFI);
  __hip_bfloat16* h1bf  = (__hip_bfloat16*)(ws + OFF_H1BFI);

  attn_partial_k<<<dim3(NSC, NB), 256, 0, stream>>>(enc, attn_w, pctx, pml);
  attn_finish_k<<<NB, 256, 0, stream>>>(pctx, pml, emb, dec, hidden,
                                        xbf, h0bf, h1bf);
  lstm_fused_k<NX><<<dim3(4, NH / 4), 128, 0, stream>>>(
      w_ih0, w_hh0, xbf, h0bf, b_ih0, b_hh0, cell,
      out + OUT_HID, out + OUT_CELL, h0nbf);
  lstm_fused_k<NH><<<dim3(4, NH / 4), 128, 0, stream>>>(
      w_ih1, w_hh1, h0nbf, h1bf, b_ih1, b_hh1, cell + NB * NH,
      out + OUT_HID + (size_t)NB * NH,
      out + OUT_CELL + (size_t)NB * NH, h1nbf);
  gemm_fc_pipe_k<<<FC_BLOCKS, 256, 0, stream>>>(h1nbf, fc_w, fc_b, out);
}